// Round 7
// baseline (728.268 us; speedup 1.0000x reference)
//
#include <hip/hip_runtime.h>
#include <hip/hip_bf16.h>
#include <math.h>

#define EPS 1e-5f

static constexpr int N_ = 128, C_ = 128, T_ = 256, V_ = 21, E_ = 8, M_ = 13;
static constexpr int TV_ = T_ * V_;        // 5376
static constexpr int NT_ = 8;              // t's per tile
static constexpr int ST_ = NT_ * V_;       // 168 s-columns per tile
static constexpr int TILE_B = 176 * 256;   // 45056 bytes per xt tile (bf16, frag-major)
static constexpr int NCHUNK = TILE_B / 1024;  // 44
static constexpr int SPITCH = 272;         // T scratch pitch (16-mult)
static constexpr int XFOFF = TILE_B;       // xf region offset in M's LDS
static constexpr int XF_BYTES = 512 * 48 + 64;  // 24640

typedef short bf16x8 __attribute__((ext_vector_type(8)));
typedef short s16x4  __attribute__((ext_vector_type(4)));
typedef float f32x4  __attribute__((ext_vector_type(4)));

__device__ inline short f2bf(float v) { __hip_bfloat16 b = __float2bfloat16(v); return *reinterpret_cast<short*>(&b); }
__device__ inline float bf2f(short s) { __hip_bfloat16 b = *reinterpret_cast<__hip_bfloat16*>(&s); return __bfloat162float(b); }
// T scratch [s][c] address with bank swizzle (16B-block XOR keyed by s>>2)
__device__ inline int saddr(int s, int c2) { return (s * SPITCH + c2) ^ (((s >> 2) & 7) << 4); }
// frag-major byte of element (s, c) within a tile
__device__ inline int fragb(int s, int c) {
    return ((c >> 5) * 11 + (s >> 4)) * 1024 + (((c >> 3) & 3) * 16 + (s & 15)) * 16 + (c & 7) * 2;
}
#define EXOR(r) ((((r) >> 5) & 3) << 4)

__device__ inline void gload16(const void* g, void* l) {
    __builtin_amdgcn_global_load_lds((const __attribute__((address_space(1))) unsigned int*)g,
                                     (__attribute__((address_space(3))) unsigned int*)l, 16, 0, 0);
}

// ---------------- Kernel P: fold BN + convert W to bf16 + zero xm ----------------
__global__ __launch_bounds__(256) void prep_kernel(
    const float* __restrict__ ft_w, const float* __restrict__ ft_b,
    const float* __restrict__ ft_gamma, const float* __restrict__ ft_beta,
    const float* __restrict__ ft_mean, const float* __restrict__ ft_var,
    __hip_bfloat16* __restrict__ w_bf, float* __restrict__ sc_g, float* __restrict__ sh_g,
    float* __restrict__ xm)
{
    int tid = blockIdx.x * 256 + threadIdx.x;        // 0..16383
    if (tid < C_ * C_) w_bf[tid] = __float2bfloat16(ft_w[tid]);
    if (tid < C_) {
        float sc = ft_gamma[tid] * rsqrtf(ft_var[tid] + EPS);
        sc_g[tid] = sc;
        sh_g[tid] = (ft_b[tid] - ft_mean[tid]) * sc + ft_beta[tid];
    }
    #pragma unroll
    for (int j = 0; j < 21; ++j) xm[tid + 16384 * j] = 0.f;   // 16384*21 == N*C*V
}

// ---------------- Kernel A (fallback path): sum over T ----------------
__global__ __launch_bounds__(256) void mean_kernel(const float* __restrict__ x,
                                                   float* __restrict__ xm) {
    __shared__ float slab[TV_];
    __shared__ float partial[V_ * 8];
    const int nc = blockIdx.x;
    const int tid = threadIdx.x;
    const float4* src4 = (const float4*)(x + (size_t)nc * TV_);
    float4* slab4 = (float4*)slab;
    #pragma unroll
    for (int it = 0; it < 6; ++it) {
        int idx = it * 256 + tid;
        if (idx < TV_ / 4) slab4[idx] = src4[idx];
    }
    __syncthreads();
    if (tid < V_ * 8) {
        int v = tid >> 3, g = tid & 7;
        float s = 0.f;
        #pragma unroll
        for (int tt = 0; tt < 32; ++tt) s += slab[(g * 32 + tt) * V_ + v];
        partial[v * 8 + g] = s;
    }
    __syncthreads();
    if (tid < V_) {
        float s = 0.f;
        #pragma unroll
        for (int g = 0; g < 8; ++g) s += partial[tid * 8 + g];
        xm[(size_t)nc * V_ + tid] = s;     // SUM (hyper scales by 1/T)
    }
}

// ---------------- Kernel T: transpose x -> xt (bf16 frag-major) [+ mean sums] ----------------
// grid (32 st, NY n), 256 threads
template<bool DO_MEAN>
__global__ __launch_bounds__(256, 4) void trans_kernel(
    const float* __restrict__ x, int n0,
    __hip_bfloat16* __restrict__ xt,      // tiles indexed (blockIdx.y*32 + st)
    float* __restrict__ xm)               // (N,C,V) sums via atomics
{
    __shared__ __align__(16) char sc[176 * SPITCH];   // 47872
    const int st = blockIdx.x;
    const int n = n0 + blockIdx.y;
    const int tid = threadIdx.x;
    const size_t xn = (size_t)n * C_ * TV_;
    const int s0 = st * ST_;

    // load fp32, convert, write scratch [s][c] bf16 (1344 items: 4c x 4s each)
    for (int r6 = 0; r6 < 6; ++r6) {
        int idx = tid + 256 * r6;
        if (idx < 1344) {
            int cg = idx / 42, q = idx - cg * 42;
            int c0 = cg * 4, sq = 4 * q;
            f32x4 f[4];
            #pragma unroll
            for (int i = 0; i < 4; ++i)
                f[i] = *(const f32x4*)(x + xn + (size_t)(c0 + i) * TV_ + s0 + sq);
            #pragma unroll
            for (int i2 = 0; i2 < 4; ++i2) {
                int s = sq + i2;
                s16x4 pk = { f2bf(f[0][i2]), f2bf(f[1][i2]), f2bf(f[2][i2]), f2bf(f[3][i2]) };
                *(s16x4*)(sc + saddr(s, c0 * 2)) = pk;
            }
        }
    }
    // zero pad rows s=168..175 (first 256 B of each row)
    if (tid < 128) {
        int row = 168 + (tid >> 4), off = (tid & 15) * 16;
        *(f32x4*)(sc + saddr(row, 0) + ((off ^ 0) )) = (f32x4){0.f, 0.f, 0.f, 0.f};
    }
    __syncthreads();

    if (DO_MEAN) {
        // thread owns channel c = tid>>1, half h = tid&1 (84 s each); bf16 partial sums
        const int c = tid >> 1, h = tid & 1;
        const int sb = 84 * h;
        float vs[V_];
        #pragma unroll
        for (int v = 0; v < V_; ++v) vs[v] = 0.f;
        #pragma unroll
        for (int t4 = 0; t4 < 4; ++t4) {
            #pragma unroll
            for (int v = 0; v < V_; ++v) {
                int s = sb + t4 * V_ + v;
                vs[v] += bf2f(*(const short*)(sc + saddr(s, c * 2)));
            }
        }
        #pragma unroll
        for (int v = 0; v < V_; ++v) {
            float tot = vs[v] + __shfl_xor(vs[v], 1);
            if (h == 0) atomicAdd(&xm[((size_t)n * C_ + c) * V_ + v], tot);
        }
    }

    // copy-out in frag-major order (coalesced 16B/lane)
    __hip_bfloat16* dst = xt + (size_t)(blockIdx.y * 32 + st) * (TILE_B / 2);
    const int wv = tid >> 6, l = tid & 63;
    #pragma unroll
    for (int k = 0; k < 11; ++k) {
        int ch = wv * 11 + k;
        int kk = ch / 11, nf = ch - 11 * kk;
        int s = nf * 16 + (l & 15);
        int c0 = kk * 32 + (l >> 4) * 8;
        f32x4 val = *(const f32x4*)(sc + saddr(s, c0 * 2));
        *(f32x4*)((char*)dst + ch * 1024 + l * 16) = val;
    }
}

// ---------------- Kernel B: H_dyn + A = H^T H (bf16, 32x32 zero-padded) ----------------
__global__ __launch_bounds__(64) void hyper_kernel(
    const float* __restrict__ xm, const float* __restrict__ dyn_w,
    const float* __restrict__ dyn_b,
    const float* __restrict__ dyn_gamma, const float* __restrict__ dyn_beta,
    const float* __restrict__ dyn_mean, const float* __restrict__ dyn_var,
    __hip_bfloat16* __restrict__ A_bf)
{
    __shared__ float xs[C_ * V_];
    __shared__ float Hs[M_ * V_];
    const int n = blockIdx.x;
    const int l = threadIdx.x;
    const float* src = xm + (size_t)n * C_ * V_;
    for (int idx = l; idx < C_ * V_; idx += 64) xs[idx] = src[idx] * (1.0f / 256.0f);
    __syncthreads();
    for (int idx = l; idx < E_ * V_; idx += 64) {
        int e = idx / V_, v = idx - e * V_;
        float acc = 0.f;
        for (int c = 0; c < C_; ++c) acc = fmaf(xs[c * V_ + v], dyn_w[e * C_ + c], acc);
        acc += dyn_b[e];
        float scale = dyn_gamma[e] * rsqrtf(dyn_var[e] + EPS);
        acc = (acc - dyn_mean[e]) * scale + dyn_beta[e];
        Hs[idx] = fmaxf(acc, 0.f);
    }
    __syncthreads();
    if (l < E_) {
        float row[V_];
        float mx = -1e30f;
        #pragma unroll
        for (int v = 0; v < V_; ++v) { row[v] = Hs[l * V_ + v]; mx = fmaxf(mx, row[v]); }
        float s = 0.f;
        #pragma unroll
        for (int v = 0; v < V_; ++v) { row[v] = __expf(row[v] - mx); s += row[v]; }
        float inv = 1.0f / s;
        #pragma unroll
        for (int v = 0; v < V_; ++v) Hs[l * V_ + v] = row[v] * inv;
    } else if (l < M_) {
        int i = l - E_;
        #pragma unroll
        for (int v = 0; v < V_; ++v)
            Hs[l * V_ + v] = (v >= 1 + 4 * i && v < 5 + 4 * i) ? 1.0f : 0.0f;
    }
    __syncthreads();
    for (int idx = l; idx < 32 * 32; idx += 64) {
        int u = idx >> 5, v = idx & 31;
        float s = 0.f;
        if (u < V_ && v < V_) {
            #pragma unroll
            for (int m = 0; m < M_; ++m) s = fmaf(Hs[m * V_ + u], Hs[m * V_ + v], s);
        }
        A_bf[(size_t)n * 1024 + idx] = __float2bfloat16(s);
    }
}

// ---------------- Kernel M: async-staged MFMA GEMM + BN/ReLU + MFMA A-transform + residual ----------------
// grid (32 st, NY n), 512 threads = 8 waves
__global__ __launch_bounds__(512, 4) void main_kernel(
    int n0, const __hip_bfloat16* __restrict__ xt,
    const __hip_bfloat16* __restrict__ w_bf,
    const float* __restrict__ sc_g, const float* __restrict__ sh_g,
    const __hip_bfloat16* __restrict__ A_bf, float* __restrict__ out)
{
    __shared__ __align__(16) char lds[TILE_B + XF_BYTES];   // 45056 + 24640 = 69696
    const int st = blockIdx.x;
    const int n = n0 + blockIdx.y;
    const int tid = threadIdx.x;
    const int w = tid >> 6, l = tid & 63;
    const int hi = l >> 4, lo = l & 15;
    const int t0 = st * NT_;
    const size_t xn = (size_t)n * C_ * TV_;

    // async stage: 44 chunks of 1024 B, wave-linear (lds dest wave-uniform, src per-lane)
    const char* tsrc = (const char*)xt + (size_t)(blockIdx.y * 32 + st) * TILE_B;
    #pragma unroll
    for (int k = 0; k < 6; ++k) {
        int ch = w + 8 * k;
        if (ch < NCHUNK) gload16(tsrc + ch * 1024 + l * 16, lds + ch * 1024);
    }

    // xf pad init (region disjoint from staging): u=21..23 of each row + 64B tail
    {
        int row = tid;   // 512 rows
        int e = EXOR(row);
        *(short*)(lds + XFOFF + ((row * 48 + 42) ^ e)) = 0;
        *(int*)(lds + XFOFF + ((row * 48 + 44) ^ e)) = 0;
        if (tid < 4) *(f32x4*)(lds + XFOFF + 24576 + tid * 16) = (f32x4){0.f, 0.f, 0.f, 0.f};
    }

    // operand fragments from global (L2-hot)
    const int o_row = 16 * w + lo;
    bf16x8 wf[4];
    #pragma unroll
    for (int kk = 0; kk < 4; ++kk)
        wf[kk] = *(const bf16x8*)((const short*)w_bf + o_row * C_ + kk * 32 + 8 * hi);
    const short* Abf_n = (const short*)A_bf + (size_t)n * 1024;
    const bf16x8 bA0 = *(const bf16x8*)(Abf_n + lo * 32 + 8 * hi);
    const bf16x8 bA1 = *(const bf16x8*)(Abf_n + (16 + lo) * 32 + 8 * hi);

    const int obase = 16 * w + 4 * hi;
    float scr[4], shr[4];
    #pragma unroll
    for (int r = 0; r < 4; ++r) { scr[r] = sc_g[obase + r]; shr[r] = sh_g[obase + r]; }

    __syncthreads();   // staging (vmcnt drained) + pad init visible

    // GEMM1: 11 N-frags, K=128; lane-linear conflict-free ds_read_b128
    f32x4 acc[11];
    #pragma unroll
    for (int nf = 0; nf < 11; ++nf) acc[nf] = (f32x4){0.f, 0.f, 0.f, 0.f};
    #pragma unroll
    for (int kk = 0; kk < 4; ++kk) {
        #pragma unroll
        for (int nf = 0; nf < 11; ++nf) {
            bf16x8 b = *(const bf16x8*)(lds + (kk * 11 + nf) * 1024 + l * 16);
            acc[nf] = __builtin_amdgcn_mfma_f32_16x16x32_bf16(wf[kk], b, acc[nf], 0, 0, 0);
        }
    }

    // two o-halves: epi(write xf) -> barrier -> GEMM2 + residual + store
    #pragma unroll
    for (int half = 0; half < 2; ++half) {
        if ((w >> 2) == half) {
            #pragma unroll
            for (int nf = 0; nf < 11; ++nf) {
                int s = 16 * nf + lo;
                if (s < ST_) {
                    int t = s / V_, u = s - t * V_;
                    #pragma unroll
                    for (int r = 0; r < 4; ++r) {
                        float vv = fmaxf(fmaf(acc[nf][r], scr[r], shr[r]), 0.f);
                        int lr = ((obase & 63) + r) * NT_ + t;
                        *(short*)(lds + XFOFF + ((lr * 48 + u * 2) ^ EXOR(lr))) = f2bf(vv);
                    }
                }
            }
        }
        __syncthreads();   // xf(half) ready

        bf16x8 xfr[4];
        #pragma unroll
        for (int i = 0; i < 4; ++i) {
            int lr = 16 * (4 * w + i) + lo;
            xfr[i] = *(const bf16x8*)(lds + XFOFF + ((lr * 48 + 16 * hi) ^ EXOR(lr)));
        }
        #pragma unroll
        for (int i = 0; i < 4; ++i) {
            f32x4 d0 = (f32x4){0.f, 0.f, 0.f, 0.f};
            f32x4 d1 = (f32x4){0.f, 0.f, 0.f, 0.f};
            d0 = __builtin_amdgcn_mfma_f32_16x16x32_bf16(xfr[i], bA0, d0, 0, 0, 0);
            d1 = __builtin_amdgcn_mfma_f32_16x16x32_bf16(xfr[i], bA1, d1, 0, 0, 0);
            int row0 = 16 * (4 * w + i) + 4 * hi;
            #pragma unroll
            for (int r = 0; r < 4; ++r) {
                int grow = half * 512 + row0 + r;
                int o = grow >> 3, tl = grow & 7;
                size_t g = xn + (size_t)o * TV_ + (size_t)(t0 + tl) * V_;
                int s1 = tl * V_ + lo;
                out[g + lo] = d0[r] + bf2f(*(const short*)(lds + fragb(s1, o)));
                if (lo < V_ - 16)
                    out[g + 16 + lo] = d1[r] + bf2f(*(const short*)(lds + fragb(s1 + 16, o)));
            }
        }
        if (half == 0) __syncthreads();   // xf reads done before half1 rewrites
    }
}

extern "C" void kernel_launch(void* const* d_in, const int* in_sizes, int n_in,
                              void* d_out, int out_size, void* d_ws, size_t ws_size,
                              hipStream_t stream) {
    const float* x         = (const float*)d_in[0];
    const float* dyn_w     = (const float*)d_in[1];
    const float* dyn_b     = (const float*)d_in[2];
    const float* dyn_gamma = (const float*)d_in[3];
    const float* dyn_beta  = (const float*)d_in[4];
    const float* dyn_mean  = (const float*)d_in[5];
    const float* dyn_var   = (const float*)d_in[6];
    const float* ft_w      = (const float*)d_in[7];
    const float* ft_b      = (const float*)d_in[8];
    const float* ft_gamma  = (const float*)d_in[9];
    const float* ft_beta   = (const float*)d_in[10];
    const float* ft_mean   = (const float*)d_in[11];
    const float* ft_var    = (const float*)d_in[12];
    float* out = (float*)d_out;

    char* ws = (char*)d_ws;
    float* xm  = (float*)ws;                     ws += (size_t)N_ * C_ * V_ * 4;   // 1,376,256
    __hip_bfloat16* A_bf = (__hip_bfloat16*)ws;  ws += (size_t)N_ * 1024 * 2;      //   262,144
    __hip_bfloat16* w_bf = (__hip_bfloat16*)ws;  ws += (size_t)C_ * C_ * 2;        //    32,768
    float* sc_g = (float*)ws;                    ws += C_ * 4;
    float* sh_g = (float*)ws;                    ws += C_ * 4;
    __hip_bfloat16* xt = (__hip_bfloat16*)ws;
    size_t fixed = (size_t)(ws - (char*)d_ws);
    size_t xt_full = (size_t)N_ * 32 * TILE_B;                 // 184,549,376

    prep_kernel<<<64, 256, 0, stream>>>(ft_w, ft_b, ft_gamma, ft_beta, ft_mean, ft_var,
                                        w_bf, sc_g, sh_g, xm);

    if (ws_size >= fixed + xt_full) {
        // full path: T (fused mean) -> hyper -> M
        trans_kernel<true><<<dim3(32, N_), 256, 0, stream>>>(x, 0, xt, xm);
        hyper_kernel<<<N_, 64, 0, stream>>>(xm, dyn_w, dyn_b, dyn_gamma, dyn_beta,
                                            dyn_mean, dyn_var, A_bf);
        main_kernel<<<dim3(32, N_), 512, 0, stream>>>(0, xt, w_bf, sc_g, sh_g, A_bf, out);
    } else {
        // sliced path: standalone mean -> hyper -> ping-pong T/M over n-slices
        mean_kernel<<<N_ * C_, 256, 0, stream>>>(x, xm);
        hyper_kernel<<<N_, 64, 0, stream>>>(xm, dyn_w, dyn_b, dyn_gamma, dyn_beta,
                                            dyn_mean, dyn_var, A_bf);
        const int NSL = 16;
        size_t sliceShorts = (size_t)NSL * 32 * (TILE_B / 2);
        for (int sl = 0; sl < N_ / NSL; ++sl) {
            __hip_bfloat16* xts = xt + (sl & 1) * sliceShorts;
            trans_kernel<false><<<dim3(32, NSL), 256, 0, stream>>>(x, sl * NSL, xts, xm);
            main_kernel<<<dim3(32, NSL), 512, 0, stream>>>(sl * NSL, xts, w_bf, sc_g, sh_g,
                                                           A_bf, out);
        }
    }
}

// Round 8
// 597.578 us; speedup vs baseline: 1.2187x; 1.2187x over previous
//
#include <hip/hip_runtime.h>
#include <hip/hip_bf16.h>
#include <math.h>

#define EPS 1e-5f

static constexpr int N_ = 128, C_ = 128, T_ = 256, V_ = 21, E_ = 8, M_ = 13;
static constexpr int TV_ = T_ * V_;   // 5376
static constexpr int NT_ = 4;         // t's per sub-tile
static constexpr int ST_ = NT_ * V_;  // 84 s-columns per sub-tile
static constexpr int NSUB = 8;        // sub-tiles per block
static constexpr int BT_ = NT_ * NSUB;  // 32 t's per block
static constexpr int SBUF = 96 * 256;   // 24576 B per staging buffer
static constexpr int XF_PITCH = 48;     // bytes per xf row

// staging swizzle: spreads writers over (s&7) and (s>>3)
#define SWZ(s)  (((((s) & 7) ^ ((((s) >> 3) & 3) << 1))) << 4)
// xf row xor (bijective within 32-row groups; identical on read & write)
#define EXOR(r) ((((r) >> 5) & 3) << 4)

typedef short bf16x8 __attribute__((ext_vector_type(8)));
typedef float f32x4  __attribute__((ext_vector_type(4)));

__device__ inline unsigned short f2bf_u(float v) {
    __hip_bfloat16 b = __float2bfloat16(v);
    return *reinterpret_cast<unsigned short*>(&b);
}
__device__ inline short f2bf(float v) {
    __hip_bfloat16 b = __float2bfloat16(v);
    return *reinterpret_cast<short*>(&b);
}

// ---------------- Kernel P: fold BN + convert W to bf16 ----------------
__global__ __launch_bounds__(256) void prep_kernel(
    const float* __restrict__ ft_w, const float* __restrict__ ft_b,
    const float* __restrict__ ft_gamma, const float* __restrict__ ft_beta,
    const float* __restrict__ ft_mean, const float* __restrict__ ft_var,
    __hip_bfloat16* __restrict__ w_bf, float* __restrict__ sc_g, float* __restrict__ sh_g)
{
    int tid = blockIdx.x * 256 + threadIdx.x;
    if (tid < C_ * C_) w_bf[tid] = __float2bfloat16(ft_w[tid]);
    if (tid < C_) {
        float sc = ft_gamma[tid] * rsqrtf(ft_var[tid] + EPS);
        sc_g[tid] = sc;
        sh_g[tid] = (ft_b[tid] - ft_mean[tid]) * sc + ft_beta[tid];
    }
}

// ---------------- Kernel A: mean over T ----------------
__global__ __launch_bounds__(256) void mean_kernel(const float* __restrict__ x,
                                                   float* __restrict__ xm) {
    __shared__ float slab[TV_];
    __shared__ float partial[V_ * 8];
    const int nc = blockIdx.x;
    const int tid = threadIdx.x;
    const float4* src4 = (const float4*)(x + (size_t)nc * TV_);
    float4* slab4 = (float4*)slab;
    #pragma unroll
    for (int it = 0; it < 6; ++it) {
        int idx = it * 256 + tid;
        if (idx < TV_ / 4) slab4[idx] = src4[idx];
    }
    __syncthreads();
    if (tid < V_ * 8) {
        int v = tid >> 3, g = tid & 7;
        float s = 0.f;
        #pragma unroll
        for (int tt = 0; tt < 32; ++tt) s += slab[(g * 32 + tt) * V_ + v];
        partial[v * 8 + g] = s;
    }
    __syncthreads();
    if (tid < V_) {
        float s = 0.f;
        #pragma unroll
        for (int g = 0; g < 8; ++g) s += partial[tid * 8 + g];
        xm[(size_t)nc * V_ + tid] = s * (1.0f / T_);
    }
}

// ---------------- Kernel B: H_dyn + A = H^T H (bf16, 32x32 zero-padded) ----------------
__global__ __launch_bounds__(64) void hyper_kernel(
    const float* __restrict__ xm, const float* __restrict__ dyn_w,
    const float* __restrict__ dyn_b,
    const float* __restrict__ dyn_gamma, const float* __restrict__ dyn_beta,
    const float* __restrict__ dyn_mean, const float* __restrict__ dyn_var,
    __hip_bfloat16* __restrict__ A_bf)
{
    __shared__ float xs[C_ * V_];
    __shared__ float Hs[M_ * V_];
    const int n = blockIdx.x;
    const int l = threadIdx.x;
    const float* src = xm + (size_t)n * C_ * V_;
    for (int idx = l; idx < C_ * V_; idx += 64) xs[idx] = src[idx];
    __syncthreads();
    for (int idx = l; idx < E_ * V_; idx += 64) {
        int e = idx / V_, v = idx - e * V_;
        float acc = 0.f;
        for (int c = 0; c < C_; ++c) acc = fmaf(xs[c * V_ + v], dyn_w[e * C_ + c], acc);
        acc += dyn_b[e];
        float scale = dyn_gamma[e] * rsqrtf(dyn_var[e] + EPS);
        acc = (acc - dyn_mean[e]) * scale + dyn_beta[e];
        Hs[idx] = fmaxf(acc, 0.f);
    }
    __syncthreads();
    if (l < E_) {
        float row[V_];
        float mx = -1e30f;
        #pragma unroll
        for (int v = 0; v < V_; ++v) { row[v] = Hs[l * V_ + v]; mx = fmaxf(mx, row[v]); }
        float s = 0.f;
        #pragma unroll
        for (int v = 0; v < V_; ++v) { row[v] = __expf(row[v] - mx); s += row[v]; }
        float inv = 1.0f / s;
        #pragma unroll
        for (int v = 0; v < V_; ++v) Hs[l * V_ + v] = row[v] * inv;
    } else if (l < M_) {
        int i = l - E_;
        #pragma unroll
        for (int v = 0; v < V_; ++v)
            Hs[l * V_ + v] = (v >= 1 + 4 * i && v < 5 + 4 * i) ? 1.0f : 0.0f;
    }
    __syncthreads();
    for (int idx = l; idx < 32 * 32; idx += 64) {
        int u = idx >> 5, v = idx & 31;
        float s = 0.f;
        if (u < V_ && v < V_) {
            #pragma unroll
            for (int m = 0; m < M_; ++m) s = fmaf(Hs[m * V_ + u], Hs[m * V_ + v], s);
        }
        A_bf[(size_t)n * 1024 + idx] = __float2bfloat16(s);
    }
}

// ---------------- Kernel C: pipelined MFMA GEMM + BN/ReLU + MFMA A-transform + residual ----------------
// grid (8 t-groups, 128 n), 512 threads = 8 waves; 8 pipelined NT=4 sub-tiles per block.
__global__ __launch_bounds__(512, 4) void main_kernel(
    const float* __restrict__ x, const __hip_bfloat16* __restrict__ w_bf,
    const float* __restrict__ sc_g, const float* __restrict__ sh_g,
    const __hip_bfloat16* __restrict__ A_bf, float* __restrict__ out)
{
    __shared__ __align__(16) char lds[2 * SBUF + 64];
    __shared__ float sc_s[C_], sh_s[C_];

    const int gt = blockIdx.x;    // 0..7
    const int n  = blockIdx.y;    // 0..127
    const int tid = threadIdx.x;
    const int w = tid >> 6, l = tid & 63;
    const int hi = l >> 4, lo = l & 15;
    const int t0 = gt * BT_;
    const float* __restrict__ xb = x + (size_t)n * C_ * TV_;   // uniform bases (SGPR)
    float* __restrict__ ob = out + (size_t)n * C_ * TV_;

    if (tid < C_) { sc_s[tid] = sc_g[tid]; sh_s[tid] = sh_g[tid]; }
    if (tid < 16) *(int*)(lds + 2 * SBUF + tid * 4) = 0;   // finite tail for row-511 frag read

    // GEMM1 A-operand (W) fragments, loaded once
    const int o_row = 16 * w + lo;
    bf16x8 wf[4];
    #pragma unroll
    for (int kk = 0; kk < 4; ++kk)
        wf[kk] = *(const bf16x8*)((const short*)w_bf + o_row * C_ + kk * 32 + 8 * hi);

    // GEMM2 B-operand (A, symmetric, zero-padded) fragments, loaded once
    const short* An = (const short*)A_bf + n * 1024;
    const bf16x8 bA0 = *(const bf16x8*)(An + lo * 32 + 8 * hi);         // v = 0..15
    const bf16x8 bA1 = *(const bf16x8*)(An + (16 + lo) * 32 + 8 * hi);  // v = 16..31

    // staging: 1344 items = 64 cg (2 c's) x 21 q (4 s's); thread does <=3 items
    const int i1 = tid + 512, i2 = tid + 1024;
    const int cgA = tid / 21, qA = tid - 21 * cgA;
    const int cgB = i1 / 21,  qB = i1 - 21 * cgB;
    const bool h3 = (i2 < 1344);
    const int cgC = h3 ? i2 / 21 : 0, qC = h3 ? (i2 - 21 * cgC) : 0;
    const int gA = 2 * cgA * TV_ + 4 * qA;   // 32-bit offsets from xb
    const int gB = 2 * cgB * TV_ + 4 * qB;
    const int gC = 2 * cgC * TV_ + 4 * qC;

    f32x4 pA0, pA1, pB0, pB1, pC0, pC1;      // 24 VGPRs of prefetch state

    auto issue = [&](int it) {
        const int tb = (t0 + NT_ * it) * V_;
        pA0 = *(const f32x4*)(xb + tb + gA);
        pA1 = *(const f32x4*)(xb + tb + gA + TV_);
        pB0 = *(const f32x4*)(xb + tb + gB);
        pB1 = *(const f32x4*)(xb + tb + gB + TV_);
        if (h3) {
            pC0 = *(const f32x4*)(xb + tb + gC);
            pC1 = *(const f32x4*)(xb + tb + gC + TV_);
        }
    };
    auto wstage = [&](char* buf) {
        #pragma unroll
        for (int i = 0; i < 4; ++i) {
            int s = 4 * qA + i;
            *(int*)(buf + ((s * 256 + 4 * cgA) ^ SWZ(s))) =
                (int)f2bf_u(pA0[i]) | ((int)f2bf_u(pA1[i]) << 16);
        }
        #pragma unroll
        for (int i = 0; i < 4; ++i) {
            int s = 4 * qB + i;
            *(int*)(buf + ((s * 256 + 4 * cgB) ^ SWZ(s))) =
                (int)f2bf_u(pB0[i]) | ((int)f2bf_u(pB1[i]) << 16);
        }
        if (h3) {
            #pragma unroll
            for (int i = 0; i < 4; ++i) {
                int s = 4 * qC + i;
                *(int*)(buf + ((s * 256 + 4 * cgC) ^ SWZ(s))) =
                    (int)f2bf_u(pC0[i]) | ((int)f2bf_u(pC1[i]) << 16);
            }
        }
        // zero pad rows s=84..95 (xf overlay corrupts them each round)
        if (tid < 384) {
            int srow = ST_ + (tid >> 5);
            int k8 = (tid & 31) * 8;
            *(unsigned long long*)(buf + ((srow * 256 + k8) ^ SWZ(srow))) = 0ull;
        }
    };

    // prologue
    issue(0);
    wstage(lds);
    __syncthreads();

    const int obase = 16 * w + 4 * hi;
    float scr[4], shr[4];
    #pragma unroll
    for (int r = 0; r < 4; ++r) { scr[r] = sc_s[obase + r]; shr[r] = sh_s[obase + r]; }

    #pragma unroll 2
    for (int it = 0; it < NSUB; ++it) {
        char* Scur = lds + (it & 1) * SBUF;
        char* Snxt = lds + ((it & 1) ^ 1) * SBUF;

        if (it < NSUB - 1) issue(it + 1);   // loads in flight across all compute below

        // GEMM1: 6 N-frags, K=128 in 4 steps
        f32x4 acc[6];
        #pragma unroll
        for (int nf = 0; nf < 6; ++nf) acc[nf] = (f32x4){0.f, 0.f, 0.f, 0.f};
        #pragma unroll
        for (int kk = 0; kk < 4; ++kk) {
            #pragma unroll
            for (int nf = 0; nf < 6; ++nf) {
                int srow = 16 * nf + lo;
                bf16x8 b = *(const bf16x8*)(Scur + ((srow * 256 + (kk * 32 + 8 * hi) * 2) ^ SWZ(srow)));
                acc[nf] = __builtin_amdgcn_mfma_f32_16x16x32_bf16(wf[kk], b, acc[nf], 0, 0, 0);
            }
        }
        __syncthreads();   // B1: GEMM1 reads (and prev GEMM2 reads) done

        // BN + ReLU -> xf bf16 overlaying Scur (rows (o*4+t) * 48 B)
        #pragma unroll
        for (int nf = 0; nf < 6; ++nf) {
            int s = 16 * nf + lo;
            if (s < ST_) {
                int t = s / V_, u = s - t * V_;
                #pragma unroll
                for (int r = 0; r < 4; ++r) {
                    float vv = fmaxf(fmaf(acc[nf][r], scr[r], shr[r]), 0.f);
                    int lr = (obase + r) * NT_ + t;
                    *(short*)(Scur + ((lr * XF_PITCH + u * 2) ^ EXOR(lr))) = f2bf(vv);
                }
            }
        }
        if (it < NSUB - 1) wstage(Snxt);    // stage next sub-tile (frees pf)
        __syncthreads();   // B2: xf + stage writes visible

        // GEMM2: Xr = xf (512x32) * A (32x32); wave w owns M-frags 4w..4w+3
        bf16x8 xfr[4];
        #pragma unroll
        for (int i = 0; i < 4; ++i) {
            int lr = 16 * (4 * w + i) + lo;
            xfr[i] = *(const bf16x8*)(Scur + ((lr * XF_PITCH + 16 * hi) ^ EXOR(lr)));
        }
        #pragma unroll
        for (int i = 0; i < 4; ++i) {
            f32x4 d0 = (f32x4){0.f, 0.f, 0.f, 0.f};
            f32x4 d1 = (f32x4){0.f, 0.f, 0.f, 0.f};
            d0 = __builtin_amdgcn_mfma_f32_16x16x32_bf16(xfr[i], bA0, d0, 0, 0, 0);
            d1 = __builtin_amdgcn_mfma_f32_16x16x32_bf16(xfr[i], bA1, d1, 0, 0, 0);
            int row0 = 16 * (4 * w + i) + 4 * hi;
            #pragma unroll
            for (int r = 0; r < 4; ++r) {
                int row = row0 + r;
                int o = row >> 2, tl = row & 3;
                int g = o * TV_ + (t0 + NT_ * it + tl) * V_;   // 32-bit offset
                ob[g + lo] = d0[r] + xb[g + lo];
                if (lo < V_ - 16) ob[g + 16 + lo] = d1[r] + xb[g + 16 + lo];
            }
        }
    }
}

extern "C" void kernel_launch(void* const* d_in, const int* in_sizes, int n_in,
                              void* d_out, int out_size, void* d_ws, size_t ws_size,
                              hipStream_t stream) {
    const float* x         = (const float*)d_in[0];
    const float* dyn_w     = (const float*)d_in[1];
    const float* dyn_b     = (const float*)d_in[2];
    const float* dyn_gamma = (const float*)d_in[3];
    const float* dyn_beta  = (const float*)d_in[4];
    const float* dyn_mean  = (const float*)d_in[5];
    const float* dyn_var   = (const float*)d_in[6];
    const float* ft_w      = (const float*)d_in[7];
    const float* ft_b      = (const float*)d_in[8];
    const float* ft_gamma  = (const float*)d_in[9];
    const float* ft_beta   = (const float*)d_in[10];
    const float* ft_mean   = (const float*)d_in[11];
    const float* ft_var    = (const float*)d_in[12];
    float* out = (float*)d_out;

    char* ws = (char*)d_ws;
    float* xm  = (float*)ws;                     ws += (size_t)N_ * C_ * V_ * 4;
    __hip_bfloat16* A_bf = (__hip_bfloat16*)ws;  ws += (size_t)N_ * 1024 * 2;
    __hip_bfloat16* w_bf = (__hip_bfloat16*)ws;  ws += (size_t)C_ * C_ * 2;
    float* sc_g = (float*)ws;                    ws += C_ * 4;
    float* sh_g = (float*)ws;                    ws += C_ * 4;

    prep_kernel<<<64, 256, 0, stream>>>(ft_w, ft_b, ft_gamma, ft_beta, ft_mean, ft_var,
                                        w_bf, sc_g, sh_g);
    mean_kernel<<<N_ * C_, 256, 0, stream>>>(x, xm);
    hyper_kernel<<<N_, 64, 0, stream>>>(xm, dyn_w, dyn_b, dyn_gamma, dyn_beta,
                                        dyn_mean, dyn_var, A_bf);
    main_kernel<<<dim3(T_ / BT_, N_), 512, 0, stream>>>(x, w_bf, sc_g, sh_g, A_bf, out);
}

// Round 10
// 434.561 us; speedup vs baseline: 1.6759x; 1.3751x over previous
//
#include <hip/hip_runtime.h>
#include <hip/hip_bf16.h>
#include <math.h>

#define EPS 1e-5f

static constexpr int N_ = 128, C_ = 128, T_ = 256, V_ = 21, E_ = 8, M_ = 13;
static constexpr int TV_ = T_ * V_;     // 5376
static constexpr int NT_ = 4;           // t's per sub-tile
static constexpr int ST_ = NT_ * V_;    // 84 s-columns per sub-tile
static constexpr int NSUB = 8;          // sub-tiles per block
static constexpr int BT_ = NT_ * NSUB;  // 32 t's per block
static constexpr int IMG_B = 43008;     // fp32 [c=128][21 x 16B granules] natural-order image
static constexpr int BFOFF = IMG_B;     // bf16 [s][c] swizzled image / xf overlay (24576 B)
static constexpr int XF_PITCH = 48;

// bf16-image swizzle (round-5 proven): spreads writers over (s&7) and (s>>3)
#define SWZ(s)  (((((s) & 7) ^ ((((s) >> 3) & 3) << 1))) << 4)
// xf row xor (bijective within 32-row groups; identical on read & write)
#define EXOR(r) ((((r) >> 5) & 3) << 4)

#define LGKM0  asm volatile("s_waitcnt lgkmcnt(0)" ::: "memory")
#define VM0    asm volatile("s_waitcnt vmcnt(0)" ::: "memory")
#define SCHED0 __builtin_amdgcn_sched_barrier(0)
#define BAR    __builtin_amdgcn_s_barrier()

typedef short bf16x8 __attribute__((ext_vector_type(8)));
typedef short s16x4  __attribute__((ext_vector_type(4)));
typedef float f32x4  __attribute__((ext_vector_type(4)));

__device__ inline short f2bf(float v) {
    __hip_bfloat16 b = __float2bfloat16(v);
    return *reinterpret_cast<short*>(&b);
}
__device__ inline void gload16(const void* g, void* l) {
    __builtin_amdgcn_global_load_lds((const __attribute__((address_space(1))) unsigned int*)g,
                                     (__attribute__((address_space(3))) unsigned int*)l, 16, 0, 0);
}

// ---------------- Kernel P: fold BN + convert W to bf16 ----------------
__global__ __launch_bounds__(256) void prep_kernel(
    const float* __restrict__ ft_w, const float* __restrict__ ft_b,
    const float* __restrict__ ft_gamma, const float* __restrict__ ft_beta,
    const float* __restrict__ ft_mean, const float* __restrict__ ft_var,
    __hip_bfloat16* __restrict__ w_bf, float* __restrict__ sc_g, float* __restrict__ sh_g)
{
    int tid = blockIdx.x * 256 + threadIdx.x;
    if (tid < C_ * C_) w_bf[tid] = __float2bfloat16(ft_w[tid]);
    if (tid < C_) {
        float sc = ft_gamma[tid] * rsqrtf(ft_var[tid] + EPS);
        sc_g[tid] = sc;
        sh_g[tid] = (ft_b[tid] - ft_mean[tid]) * sc + ft_beta[tid];
    }
}

// ---------------- Kernel A: mean over T ----------------
__global__ __launch_bounds__(256) void mean_kernel(const float* __restrict__ x,
                                                   float* __restrict__ xm) {
    __shared__ float slab[TV_];
    __shared__ float partial[V_ * 8];
    const int nc = blockIdx.x;
    const int tid = threadIdx.x;
    const float4* src4 = (const float4*)(x + (size_t)nc * TV_);
    float4* slab4 = (float4*)slab;
    #pragma unroll
    for (int it = 0; it < 6; ++it) {
        int idx = it * 256 + tid;
        if (idx < TV_ / 4) slab4[idx] = src4[idx];
    }
    __syncthreads();
    if (tid < V_ * 8) {
        int v = tid >> 3, g = tid & 7;
        float s = 0.f;
        #pragma unroll
        for (int tt = 0; tt < 32; ++tt) s += slab[(g * 32 + tt) * V_ + v];
        partial[v * 8 + g] = s;
    }
    __syncthreads();
    if (tid < V_) {
        float s = 0.f;
        #pragma unroll
        for (int g = 0; g < 8; ++g) s += partial[tid * 8 + g];
        xm[(size_t)nc * V_ + tid] = s * (1.0f / T_);
    }
}

// ---------------- Kernel B: H_dyn + A = H^T H (bf16, 32x32 zero-padded) ----------------
__global__ __launch_bounds__(64) void hyper_kernel(
    const float* __restrict__ xm, const float* __restrict__ dyn_w,
    const float* __restrict__ dyn_b,
    const float* __restrict__ dyn_gamma, const float* __restrict__ dyn_beta,
    const float* __restrict__ dyn_mean, const float* __restrict__ dyn_var,
    __hip_bfloat16* __restrict__ A_bf)
{
    __shared__ float xs[C_ * V_];
    __shared__ float Hs[M_ * V_];
    const int n = blockIdx.x;
    const int l = threadIdx.x;
    const float* src = xm + (size_t)n * C_ * V_;
    for (int idx = l; idx < C_ * V_; idx += 64) xs[idx] = src[idx];
    __syncthreads();
    for (int idx = l; idx < E_ * V_; idx += 64) {
        int e = idx / V_, v = idx - e * V_;
        float acc = 0.f;
        for (int c = 0; c < C_; ++c) acc = fmaf(xs[c * V_ + v], dyn_w[e * C_ + c], acc);
        acc += dyn_b[e];
        float scale = dyn_gamma[e] * rsqrtf(dyn_var[e] + EPS);
        acc = (acc - dyn_mean[e]) * scale + dyn_beta[e];
        Hs[idx] = fmaxf(acc, 0.f);
    }
    __syncthreads();
    if (l < E_) {
        float row[V_];
        float mx = -1e30f;
        #pragma unroll
        for (int v = 0; v < V_; ++v) { row[v] = Hs[l * V_ + v]; mx = fmaxf(mx, row[v]); }
        float s = 0.f;
        #pragma unroll
        for (int v = 0; v < V_; ++v) { row[v] = __expf(row[v] - mx); s += row[v]; }
        float inv = 1.0f / s;
        #pragma unroll
        for (int v = 0; v < V_; ++v) Hs[l * V_ + v] = row[v] * inv;
    } else if (l < M_) {
        int i = l - E_;
        #pragma unroll
        for (int v = 0; v < V_; ++v)
            Hs[l * V_ + v] = (v >= 1 + 4 * i && v < 5 + 4 * i) ? 1.0f : 0.0f;
    }
    __syncthreads();
    for (int idx = l; idx < 32 * 32; idx += 64) {
        int u = idx >> 5, v = idx & 31;
        float s = 0.f;
        if (u < V_ && v < V_) {
            #pragma unroll
            for (int m = 0; m < M_; ++m) s = fmaf(Hs[m * V_ + u], Hs[m * V_ + v], s);
        }
        A_bf[(size_t)n * 1024 + idx] = __float2bfloat16(s);
    }
}

// ---------------- Kernel C: DMA-staged pipelined MFMA kernel ----------------
// grid (8 gt, 128 n), 512 threads = 8 waves; 8 sub-tiles of NT=4 t's each.
// Per sub-tile: [DMA next fp32 tile async] || [LDS transpose->bf16, GEMM1, BN/ReLU->xf, GEMM2+residual+store]
__global__ __launch_bounds__(512, 4) void main_kernel(
    const float* __restrict__ x, const __hip_bfloat16* __restrict__ w_bf,
    const float* __restrict__ sc_g, const float* __restrict__ sh_g,
    const __hip_bfloat16* __restrict__ A_bf, float* __restrict__ out)
{
    // IMG fp32 (43008) + BF/XF bf16 overlay (24576) + 64-B zeroed tail
    __shared__ __align__(16) char lds[IMG_B + 24576 + 64];
    __shared__ float sc_s[C_], sh_s[C_];

    const int gt = blockIdx.x;
    const int n  = blockIdx.y;
    const int tid = threadIdx.x;
    const int w = tid >> 6, l = tid & 63;
    const int hi = l >> 4, lo = l & 15;
    const int t0 = gt * BT_;
    const float* __restrict__ xb = x + (size_t)n * C_ * TV_;
    float* __restrict__ ob = out + (size_t)n * C_ * TV_;
    const char* xcb = (const char*)xb;

    // DMA chunk global offsets (invariant across sub-tiles)
    int dmaoff[6];
    #pragma unroll
    for (int k = 0; k < 6; ++k) {
        int ch = w + 8 * k;
        if (ch < 42) {
            int cell = ch * 64 + l;
            int c = cell / 21, q = cell - 21 * c;
            dmaoff[k] = c * (TV_ * 4) + 16 * q;
        } else dmaoff[k] = 0;
    }
    auto dma = [&](int it) {
        const int tb = (t0 + NT_ * it) * (V_ * 4);
        #pragma unroll
        for (int k = 0; k < 6; ++k) {
            int ch = w + 8 * k;
            if (ch < 42) gload16(xcb + tb + dmaoff[k], lds + ch * 1024);
        }
    };
    // LDS transpose+convert: IMG [c][s] fp32 -> BF [s][c] bf16 (swizzled). 672 quad-items.
    auto trquad = [&](int j) {
        int cb = j / 21, q = j - 21 * cb;       // cb: 4-channel group, q: 4-s granule
        const char* base = lds + cb * 1344 + 16 * q;
        f32x4 f0 = *(const f32x4*)(base);
        f32x4 f1 = *(const f32x4*)(base + 336);
        f32x4 f2 = *(const f32x4*)(base + 672);
        f32x4 f3 = *(const f32x4*)(base + 1008);
        #pragma unroll
        for (int si = 0; si < 4; ++si) {
            int s = 4 * q + si;
            s16x4 pk = { f2bf(f0[si]), f2bf(f1[si]), f2bf(f2[si]), f2bf(f3[si]) };
            *(s16x4*)(lds + BFOFF + ((s * 256 + 8 * cb) ^ SWZ(s))) = pk;
        }
    };

    // prologue: DMA sub-tile 0; zero BF rows 84..95 + tail (the only bytes that
    // can feed GEMM2's zero-padded K columns and are never rewritten); W/A frags.
    dma(0);
    if (tid < 196) *(f32x4*)(lds + BFOFF + 21504 + 16 * tid) = (f32x4){0.f, 0.f, 0.f, 0.f};
    if (tid < C_) { sc_s[tid] = sc_g[tid]; sh_s[tid] = sh_g[tid]; }
    const int o_row = 16 * w + lo;
    bf16x8 wf[4];
    #pragma unroll
    for (int kk = 0; kk < 4; ++kk)
        wf[kk] = *(const bf16x8*)((const short*)w_bf + o_row * C_ + kk * 32 + 8 * hi);
    const short* An = (const short*)A_bf + n * 1024;
    const bf16x8 bA0 = *(const bf16x8*)(An + lo * 32 + 8 * hi);         // v = 0..15
    const bf16x8 bA1 = *(const bf16x8*)(An + (16 + lo) * 32 + 8 * hi);  // v = 16..31
    __syncthreads();   // full drain: IMG(0) + zeroing + sc_s visible

    const int obase = 16 * w + 4 * hi;
    float scr[4], shr[4];
    #pragma unroll
    for (int r = 0; r < 4; ++r) { scr[r] = sc_s[obase + r]; shr[r] = sh_s[obase + r]; }

    #pragma unroll 1
    for (int it = 0; it < NSUB; ++it) {
        // ---- transpose IMG -> BF ----
        trquad(tid);
        if (tid < 160) trquad(512 + tid);
        LGKM0; SCHED0; BAR; SCHED0;            // BF visible; IMG fully consumed

        if (it < NSUB - 1) dma(it + 1);        // async refill of IMG under all compute below

        // ---- GEMM1: 6 N-frags, K=128 in 4 steps ----
        f32x4 acc[6];
        #pragma unroll
        for (int nf = 0; nf < 6; ++nf) acc[nf] = (f32x4){0.f, 0.f, 0.f, 0.f};
        #pragma unroll
        for (int kk = 0; kk < 4; ++kk) {
            #pragma unroll
            for (int nf = 0; nf < 6; ++nf) {
                int srow = 16 * nf + lo;
                bf16x8 b = *(const bf16x8*)(lds + BFOFF +
                            ((srow * 256 + (kk * 32 + 8 * hi) * 2) ^ SWZ(srow)));
                acc[nf] = __builtin_amdgcn_mfma_f32_16x16x32_bf16(wf[kk], b, acc[nf], 0, 0, 0);
            }
        }
        SCHED0; BAR; SCHED0;                   // GEMM1 reads done (MFMA consumption forces lgkm drain)

        // ---- BN + ReLU -> xf bf16 overlaying BF ----
        #pragma unroll
        for (int nf = 0; nf < 6; ++nf) {
            int s = 16 * nf + lo;
            if (s < ST_) {
                int t = s / V_, u = s - t * V_;
                #pragma unroll
                for (int r = 0; r < 4; ++r) {
                    float vv = fmaxf(fmaf(acc[nf][r], scr[r], shr[r]), 0.f);
                    int lr = (obase + r) * NT_ + t;
                    *(short*)(lds + BFOFF + ((lr * XF_PITCH + u * 2) ^ EXOR(lr))) = f2bf(vv);
                }
            }
        }
        LGKM0; SCHED0; BAR; SCHED0;            // XF visible

        // ---- GEMM2 + residual + store ----
        bf16x8 xfr[4];
        #pragma unroll
        for (int i = 0; i < 4; ++i) {
            int lr = 16 * (4 * w + i) + lo;
            xfr[i] = *(const bf16x8*)(lds + BFOFF + ((lr * XF_PITCH + 16 * hi) ^ EXOR(lr)));
        }
        #pragma unroll
        for (int i = 0; i < 4; ++i) {
            f32x4 d0 = (f32x4){0.f, 0.f, 0.f, 0.f};
            f32x4 d1 = (f32x4){0.f, 0.f, 0.f, 0.f};
            d0 = __builtin_amdgcn_mfma_f32_16x16x32_bf16(xfr[i], bA0, d0, 0, 0, 0);
            d1 = __builtin_amdgcn_mfma_f32_16x16x32_bf16(xfr[i], bA1, d1, 0, 0, 0);
            int row0 = 16 * (4 * w + i) + 4 * hi;
            #pragma unroll
            for (int r = 0; r < 4; ++r) {
                int row = row0 + r;
                int o = row >> 2, tl = row & 3;
                int g = o * TV_ + (t0 + NT_ * it + tl) * V_;
                ob[g + lo] = d0[r] + xb[g + lo];
                if (lo < V_ - 16) ob[g + 16 + lo] = d1[r] + xb[g + 16 + lo];
            }
        }
        VM0; SCHED0; BAR; SCHED0;              // DMA(it+1) complete; IMG ready for next transpose
    }
}

extern "C" void kernel_launch(void* const* d_in, const int* in_sizes, int n_in,
                              void* d_out, int out_size, void* d_ws, size_t ws_size,
                              hipStream_t stream) {
    const float* x         = (const float*)d_in[0];
    const float* dyn_w     = (const float*)d_in[1];
    const float* dyn_b     = (const float*)d_in[2];
    const float* dyn_gamma = (const float*)d_in[3];
    const float* dyn_beta  = (const float*)d_in[4];
    const float* dyn_mean  = (const float*)d_in[5];
    const float* dyn_var   = (const float*)d_in[6];
    const float* ft_w      = (const float*)d_in[7];
    const float* ft_b      = (const float*)d_in[8];
    const float* ft_gamma  = (const float*)d_in[9];
    const float* ft_beta   = (const float*)d_in[10];
    const float* ft_mean   = (const float*)d_in[11];
    const float* ft_var    = (const float*)d_in[12];
    float* out = (float*)d_out;

    char* ws = (char*)d_ws;
    float* xm  = (float*)ws;                     ws += (size_t)N_ * C_ * V_ * 4;
    __hip_bfloat16* A_bf = (__hip_bfloat16*)ws;  ws += (size_t)N_ * 1024 * 2;
    __hip_bfloat16* w_bf = (__hip_bfloat16*)ws;  ws += (size_t)C_ * C_ * 2;
    float* sc_g = (float*)ws;                    ws += C_ * 4;
    float* sh_g = (float*)ws;                    ws += C_ * 4;

    prep_kernel<<<64, 256, 0, stream>>>(ft_w, ft_b, ft_gamma, ft_beta, ft_mean, ft_var,
                                        w_bf, sc_g, sh_g);
    mean_kernel<<<N_ * C_, 256, 0, stream>>>(x, xm);
    hyper_kernel<<<N_, 64, 0, stream>>>(xm, dyn_w, dyn_b, dyn_gamma, dyn_beta,
                                        dyn_mean, dyn_var, A_bf);
    main_kernel<<<dim3(T_ / BT_, N_), 512, 0, stream>>>(x, w_bf, sc_g, sh_g, A_bf, out);
}

// Round 11
// 341.948 us; speedup vs baseline: 2.1298x; 1.2708x over previous
//
#include <hip/hip_runtime.h>
#include <hip/hip_bf16.h>
#include <math.h>

#define EPS 1e-5f

static constexpr int N_ = 128, C_ = 128, T_ = 256, V_ = 21, E_ = 8, M_ = 13;
static constexpr int TV_ = T_ * V_;   // 5376
static constexpr int NT_ = 8;         // t's per main-kernel tile
static constexpr int ST_ = NT_ * V_;  // 168 s-columns per tile
static constexpr int XF_PITCH = 48;   // bytes per xf row (24 bf16 slots, 21 used)

// staging swizzle: 16-slot spread keyed by (s>>3, s&7); bijective within each 256B row
#define SWZ(s)  (((((s) >> 3) & 15) ^ ((((s) & 7)) << 1)) << 4)
// xf row xor (bijective: 32-row groups are 64B-aligned multiples; same on read & write)
#define EXOR(r) ((((r) >> 5) & 3) << 4)

typedef short bf16x8 __attribute__((ext_vector_type(8)));
typedef short s16x4  __attribute__((ext_vector_type(4)));
typedef float f32x4  __attribute__((ext_vector_type(4)));

__device__ inline short f2bf(float v) {
    __hip_bfloat16 b = __float2bfloat16(v);
    return *reinterpret_cast<short*>(&b);
}
__device__ inline float bf2f_u(unsigned short s) {
    __hip_bfloat16 b = *reinterpret_cast<__hip_bfloat16*>(&s);
    return __bfloat162float(b);
}

// ---------------- Kernel P: fold BN + convert W to bf16 ----------------
__global__ __launch_bounds__(256) void prep_kernel(
    const float* __restrict__ ft_w, const float* __restrict__ ft_b,
    const float* __restrict__ ft_gamma, const float* __restrict__ ft_beta,
    const float* __restrict__ ft_mean, const float* __restrict__ ft_var,
    __hip_bfloat16* __restrict__ w_bf, float* __restrict__ sc_g, float* __restrict__ sh_g)
{
    int tid = blockIdx.x * 256 + threadIdx.x;
    if (tid < C_ * C_) w_bf[tid] = __float2bfloat16(ft_w[tid]);
    if (tid < C_) {
        float sc = ft_gamma[tid] * rsqrtf(ft_var[tid] + EPS);
        sc_g[tid] = sc;
        sh_g[tid] = (ft_b[tid] - ft_mean[tid]) * sc + ft_beta[tid];
    }
}

// ---------------- Kernel CV: x -> bf16 copy + mean over T ----------------
// grid N*C blocks, 256 threads; one (n,c) slab each.
__global__ __launch_bounds__(256) void cvt_kernel(const float* __restrict__ x,
                                                  __hip_bfloat16* __restrict__ xbf,
                                                  float* __restrict__ xm) {
    __shared__ float slab[TV_];
    __shared__ float partial[V_ * 8];
    const int nc = blockIdx.x;
    const int tid = threadIdx.x;
    const f32x4* src4 = (const f32x4*)(x + (size_t)nc * TV_);
    f32x4* slab4 = (f32x4*)slab;
    short* dst = (short*)xbf + (size_t)nc * TV_;

    // 1344 f32x4 granules as 672 pairs: convert+store 16B bf16, keep fp32 in slab for mean
    #pragma unroll
    for (int it = 0; it < 3; ++it) {
        int p = it * 256 + tid;            // pair index 0..767 (<672 valid)
        if (p < 672) {
            f32x4 a = src4[2 * p], b = src4[2 * p + 1];
            slab4[2 * p] = a; slab4[2 * p + 1] = b;
            bf16x8 pk = { f2bf(a[0]), f2bf(a[1]), f2bf(a[2]), f2bf(a[3]),
                          f2bf(b[0]), f2bf(b[1]), f2bf(b[2]), f2bf(b[3]) };
            *(bf16x8*)(dst + 8 * p) = pk;
        }
    }
    __syncthreads();
    if (tid < V_ * 8) {
        int v = tid >> 3, g = tid & 7;
        float s = 0.f;
        #pragma unroll
        for (int tt = 0; tt < 32; ++tt) s += slab[(g * 32 + tt) * V_ + v];
        partial[v * 8 + g] = s;
    }
    __syncthreads();
    if (tid < V_) {
        float s = 0.f;
        #pragma unroll
        for (int g = 0; g < 8; ++g) s += partial[tid * 8 + g];
        xm[(size_t)nc * V_ + tid] = s * (1.0f / T_);
    }
}

// ---------------- Kernel B: H_dyn + A = H^T H (bf16, 32x32 zero-padded) ----------------
__global__ __launch_bounds__(64) void hyper_kernel(
    const float* __restrict__ xm, const float* __restrict__ dyn_w,
    const float* __restrict__ dyn_b,
    const float* __restrict__ dyn_gamma, const float* __restrict__ dyn_beta,
    const float* __restrict__ dyn_mean, const float* __restrict__ dyn_var,
    __hip_bfloat16* __restrict__ A_bf)
{
    __shared__ float xs[C_ * V_];
    __shared__ float Hs[M_ * V_];
    const int n = blockIdx.x;
    const int l = threadIdx.x;
    const float* src = xm + (size_t)n * C_ * V_;
    for (int idx = l; idx < C_ * V_; idx += 64) xs[idx] = src[idx];
    __syncthreads();
    for (int idx = l; idx < E_ * V_; idx += 64) {
        int e = idx / V_, v = idx - e * V_;
        float acc = 0.f;
        for (int c = 0; c < C_; ++c) acc = fmaf(xs[c * V_ + v], dyn_w[e * C_ + c], acc);
        acc += dyn_b[e];
        float scale = dyn_gamma[e] * rsqrtf(dyn_var[e] + EPS);
        acc = (acc - dyn_mean[e]) * scale + dyn_beta[e];
        Hs[idx] = fmaxf(acc, 0.f);
    }
    __syncthreads();
    if (l < E_) {
        float row[V_];
        float mx = -1e30f;
        #pragma unroll
        for (int v = 0; v < V_; ++v) { row[v] = Hs[l * V_ + v]; mx = fmaxf(mx, row[v]); }
        float s = 0.f;
        #pragma unroll
        for (int v = 0; v < V_; ++v) { row[v] = __expf(row[v] - mx); s += row[v]; }
        float inv = 1.0f / s;
        #pragma unroll
        for (int v = 0; v < V_; ++v) Hs[l * V_ + v] = row[v] * inv;
    } else if (l < M_) {
        int i = l - E_;
        #pragma unroll
        for (int v = 0; v < V_; ++v)
            Hs[l * V_ + v] = (v >= 1 + 4 * i && v < 5 + 4 * i) ? 1.0f : 0.0f;
    }
    __syncthreads();
    for (int idx = l; idx < 32 * 32; idx += 64) {
        int u = idx >> 5, v = idx & 31;
        float s = 0.f;
        if (u < V_ && v < V_) {
            #pragma unroll
            for (int m = 0; m < M_; ++m) s = fmaf(Hs[m * V_ + u], Hs[m * V_ + v], s);
        }
        A_bf[(size_t)n * 1024 + idx] = __float2bfloat16(s);
    }
}

// ---------------- Kernel C: MFMA GEMM + BN/ReLU + MFMA A-transform + residual ----------------
// Round-4 structure (single NT=8 tile per block, proven), bf16 input.
// grid (32 s-tiles, 128 n), 512 threads = 8 waves. Wave w owns o in [16w, 16w+16).
__global__ __launch_bounds__(512) void main_kernel(
    const __hip_bfloat16* __restrict__ xbf, const __hip_bfloat16* __restrict__ w_bf,
    const float* __restrict__ sc_g, const float* __restrict__ sh_g,
    const __hip_bfloat16* __restrict__ A_bf, float* __restrict__ out)
{
    // phase 1: X_t[s=176][c=128] bf16 swizzled (45056 B)
    // phase 2: xf[(o*8+t)=1024][24 bf16] pitch 48 B (49152 B) + 128 B zeroed tail
    __shared__ __align__(16) char lds[49280];
    __shared__ float sc_s[C_], sh_s[C_];

    const int st = blockIdx.x;
    const int n  = blockIdx.y;
    const int tid = threadIdx.x;
    const int w = tid >> 6;       // wave 0..7
    const int l = tid & 63;
    const int hi = l >> 4;        // 0..3
    const int lo = l & 15;
    const int s0 = st * ST_;
    const unsigned short* xr = (const unsigned short*)xbf + (size_t)n * C_ * TV_;
    float* ob = out + (size_t)n * C_ * TV_;

    if (tid < C_) { sc_s[tid] = sc_g[tid]; sh_s[tid] = sh_g[tid]; }

    // W fragments (GEMM1 A-operand): lane holds W[16w+lo][kk*32 + 8*hi + j]
    const int o_row = 16 * w + lo;
    bf16x8 wf[4];
    #pragma unroll
    for (int kk = 0; kk < 4; ++kk)
        wf[kk] = *(const bf16x8*)((const short*)w_bf + o_row * C_ + kk * 32 + 8 * hi);

    // GEMM2 B-fragments (A symmetric, zero-padded 32x32, L2-hot)
    const short* An = (const short*)A_bf + n * 1024;
    const bf16x8 bA0 = *(const bf16x8*)(An + lo * 32 + 8 * hi);         // v = 0..15
    const bf16x8 bA1 = *(const bf16x8*)(An + (16 + lo) * 32 + 8 * hi);  // v = 16..31

    // ---- stage X_t[s][c] from bf16 source: 672 items of 4c x 8s ----
    auto stage_item = [&](int idx) {
        int cg = idx / 21, q = idx - 21 * cg;
        int c0 = 4 * cg, sb = 8 * q;
        const unsigned short* p = xr + c0 * TV_ + s0 + sb;
        bf16x8 r0 = *(const bf16x8*)(p);
        bf16x8 r1 = *(const bf16x8*)(p + TV_);
        bf16x8 r2 = *(const bf16x8*)(p + 2 * TV_);
        bf16x8 r3 = *(const bf16x8*)(p + 3 * TV_);
        #pragma unroll
        for (int si = 0; si < 8; ++si) {
            int s = sb + si;
            s16x4 pk = { r0[si], r1[si], r2[si], r3[si] };
            *(s16x4*)(lds + ((s * 256 + 8 * cg) ^ SWZ(s))) = pk;
        }
    };
    stage_item(tid);
    if (tid < 672 - 512) stage_item(tid + 512);
    // zero pad rows s = 168..175 (XOR permutes within row -> linear zero covers them)
    if (tid < 128) *(f32x4*)(lds + 168 * 256 + 16 * tid) = (f32x4){0.f, 0.f, 0.f, 0.f};
    __syncthreads();

    // ---- GEMM1: 11 N-frags, K = 128 in 4 steps ----
    f32x4 acc[11];
    #pragma unroll
    for (int nf = 0; nf < 11; ++nf) acc[nf] = (f32x4){0.f, 0.f, 0.f, 0.f};
    #pragma unroll
    for (int kk = 0; kk < 4; ++kk) {
        #pragma unroll
        for (int nf = 0; nf < 11; ++nf) {
            int srow = 16 * nf + lo;
            bf16x8 b = *(const bf16x8*)(lds + ((srow * 256 + (kk * 32 + 8 * hi) * 2) ^ SWZ(srow)));
            acc[nf] = __builtin_amdgcn_mfma_f32_16x16x32_bf16(wf[kk], b, acc[nf], 0, 0, 0);
        }
    }
    __syncthreads();   // staging reads complete; buffer becomes xf

    // ---- BN + ReLU -> xf bf16 at row (o*8+t), pitch 48 B, row-xor EXOR ----
    const int obase = 16 * w + 4 * hi;
    float scr[4], shr[4];
    #pragma unroll
    for (int r = 0; r < 4; ++r) { scr[r] = sc_s[obase + r]; shr[r] = sh_s[obase + r]; }
    #pragma unroll
    for (int nf = 0; nf < 11; ++nf) {
        int s = 16 * nf + lo;
        if (s < ST_) {
            int t = s / V_, u = s - t * V_;
            #pragma unroll
            for (int r = 0; r < 4; ++r) {
                float vv = fmaxf(fmaf(acc[nf][r], scr[r], shr[r]), 0.f);
                int row = (obase + r) * NT_ + t;
                *(short*)(lds + ((row * XF_PITCH + 2 * u) ^ EXOR(row))) = f2bf(vv);
            }
        }
    }
    // zero u=21..23 pad of both of this thread's rows + 128 B tail (finite for k>=21 reads)
    {
        int row = tid;
        *(short*)(lds + ((row * XF_PITCH + 42) ^ EXOR(row))) = 0;
        *(int*)(lds + ((row * XF_PITCH + 44) ^ EXOR(row))) = 0;
        row = tid + 512;
        *(short*)(lds + ((row * XF_PITCH + 42) ^ EXOR(row))) = 0;
        *(int*)(lds + ((row * XF_PITCH + 44) ^ EXOR(row))) = 0;
    }
    if (tid < 8) *(f32x4*)(lds + 49152 + 16 * tid) = (f32x4){0.f, 0.f, 0.f, 0.f};
    __syncthreads();

    // ---- GEMM2: Xr = xf (1024x32) * A (32x32); wave w owns M-frags 8w..8w+7 ----
    bf16x8 xfr[8];
    #pragma unroll
    for (int i = 0; i < 8; ++i) {
        int lr = 16 * (8 * w + i) + lo;
        xfr[i] = *(const bf16x8*)(lds + ((lr * XF_PITCH + 16 * hi) ^ EXOR(lr)));
    }
    #pragma unroll
    for (int i = 0; i < 8; ++i) {
        f32x4 d0 = (f32x4){0.f, 0.f, 0.f, 0.f};
        f32x4 d1 = (f32x4){0.f, 0.f, 0.f, 0.f};
        d0 = __builtin_amdgcn_mfma_f32_16x16x32_bf16(xfr[i], bA0, d0, 0, 0, 0);
        d1 = __builtin_amdgcn_mfma_f32_16x16x32_bf16(xfr[i], bA1, d1, 0, 0, 0);
        int row0 = 16 * (8 * w + i) + 4 * hi;
        #pragma unroll
        for (int r = 0; r < 4; ++r) {
            int row = row0 + r;
            int o = row >> 3, tl = row & 7;
            int g = o * TV_ + s0 + tl * V_;       // 32-bit offset from per-n base
            ob[g + lo] = d0[r] + bf2f_u(xr[g + lo]);
            if (lo < V_ - 16) ob[g + 16 + lo] = d1[r] + bf2f_u(xr[g + 16 + lo]);
        }
    }
}

extern "C" void kernel_launch(void* const* d_in, const int* in_sizes, int n_in,
                              void* d_out, int out_size, void* d_ws, size_t ws_size,
                              hipStream_t stream) {
    const float* x         = (const float*)d_in[0];
    const float* dyn_w     = (const float*)d_in[1];
    const float* dyn_b     = (const float*)d_in[2];
    const float* dyn_gamma = (const float*)d_in[3];
    const float* dyn_beta  = (const float*)d_in[4];
    const float* dyn_mean  = (const float*)d_in[5];
    const float* dyn_var   = (const float*)d_in[6];
    const float* ft_w      = (const float*)d_in[7];
    const float* ft_b      = (const float*)d_in[8];
    const float* ft_gamma  = (const float*)d_in[9];
    const float* ft_beta   = (const float*)d_in[10];
    const float* ft_mean   = (const float*)d_in[11];
    const float* ft_var    = (const float*)d_in[12];
    float* out = (float*)d_out;

    char* ws = (char*)d_ws;
    float* xm  = (float*)ws;                     ws += (size_t)N_ * C_ * V_ * 4;   // 1,376,256
    __hip_bfloat16* A_bf = (__hip_bfloat16*)ws;  ws += (size_t)N_ * 1024 * 2;      //   262,144
    __hip_bfloat16* w_bf = (__hip_bfloat16*)ws;  ws += (size_t)C_ * C_ * 2;        //    32,768
    float* sc_g = (float*)ws;                    ws += C_ * 4;
    float* sh_g = (float*)ws;                    ws += C_ * 4;
    __hip_bfloat16* xbf = (__hip_bfloat16*)ws;   // N*C*T*V*2 = 172 MB (ws proven >= 186 MB)

    prep_kernel<<<64, 256, 0, stream>>>(ft_w, ft_b, ft_gamma, ft_beta, ft_mean, ft_var,
                                        w_bf, sc_g, sh_g);
    cvt_kernel<<<N_ * C_, 256, 0, stream>>>(x, xbf, xm);
    hyper_kernel<<<N_, 64, 0, stream>>>(xm, dyn_w, dyn_b, dyn_gamma, dyn_beta,
                                        dyn_mean, dyn_var, A_bf);
    main_kernel<<<dim3(32, 128), 512, 0, stream>>>(xbf, w_bf, sc_g, sh_g, A_bf, out);
}